// Round 18
// baseline (704.226 us; speedup 1.0000x reference)
//
#include <hip/hip_runtime.h>

typedef unsigned short u16;
typedef unsigned int u32;
typedef unsigned long long u64;
typedef __attribute__((ext_vector_type(4))) float f32x4;
typedef __attribute__((ext_vector_type(8))) short s16x8;
typedef __attribute__((ext_vector_type(4))) int i32x4;

#define EPS 1e-5f

// ---------- helpers ----------
__device__ __forceinline__ u16 f2bf(float f) {
  unsigned u = __float_as_uint(f);
  return (u16)((u + 0x7fffu + ((u >> 16) & 1u)) >> 16);
}
__device__ __forceinline__ float sigm(float x) { return 1.0f / (1.0f + __expf(-x)); }
__device__ __forceinline__ float tanh_f(float x) {
  float e = __expf(-2.0f * fabsf(x));
  float r = (1.0f - e) / (1.0f + e);
  return copysignf(r, x);
}
__device__ __forceinline__ void gl_lds16(const void* g, void* l) {
  __builtin_amdgcn_global_load_lds(
      (const __attribute__((address_space(1))) u32*)g,
      (__attribute__((address_space(3))) u32*)l, 16, 0, 0);
}

// ---------- merged setup: weight pack + x transpose + zero (identical to R17) ----------
// bid<1920: wcvt; 1920..2943: xtrans; 2944..3455: zero hT/cx/flags
__global__ __launch_bounds__(256) void k_setup(
    const float* __restrict__ cw, u16* __restrict__ Wpk,
    const float* __restrict__ x, u16* __restrict__ xT,
    i32x4* __restrict__ hTz, i32x4* __restrict__ cxz, i32x4* __restrict__ flz) {
  const int bid = blockIdx.x, tid = threadIdx.x;
  __shared__ __align__(16) u16 ltile[256 * 72];
  if (bid < 1920) {
    // of = gate-ch>>4 = g*8 + ch16 ; o = of*16 + (lane&15)
    // A[o][c]: c = kk*32 + (lane>>4)*8 + j ; element = lane*8+j
    // permuted pos: newpos = (ch16>>1)*8 + (ch16&1)*4 + g -> 4 gate-frags contiguous (4KB)
    int idx = bid * 256 + tid;                 // exactly 491520
    int f = idx >> 9, r = idx & 511;
    int lane = r >> 3, j = r & 7;
    int of = f & 31, tk = f >> 5;
    int kk = tk % 6, tap = tk / 6;
    int o = (of << 4) + (lane & 15);
    int c = (kk << 5) + ((lane >> 4) << 3) + j;
    int g = of >> 3, cs = (of >> 1) & 3, wm = of & 1;
    int newpos = (cs << 3) + (wm << 2) + g;
    Wpk[(((tk << 5) + newpos) << 9) + r] = f2bf(cw[(o * 192 + c) * 5 + tap]);
  } else if (bid < 2944) {
    // x (t,b,64,256) f32 -> xT[t*32+b][264 rows][64 ch] bf16, swizzled, halos zeroed
    int tb = bid - 1920;
    const float* src = x + tb * (64 * 256);
    for (int it = 0; it < 64; ++it) {
      int idx = it * 256 + tid;
      int c = idx >> 8, l = idx & 255;
      ltile[l * 72 + c] = f2bf(src[idx]);
    }
    __syncthreads();
    char* dst = (char*)(xT + tb * 16896);
    i32x4 z = {0, 0, 0, 0};
    for (int i = tid; i < 2112; i += 256) {    // 264 rows x 8 chunks
      int r = i >> 3, ch = i & 7;
      i32x4 v = z;
      if (r >= 2 && r < 258) v = *(const i32x4*)(ltile + (r - 2) * 72 + ch * 8);
      *(i32x4*)(dst + r * 128 + ((ch * 16) ^ ((r & 7) << 4))) = v;
    }
  } else {
    int base = (bid - 2944) * 256 + tid;       // 131072 threads
    i32x4 z = {0, 0, 0, 0};
    for (int i = base; i < 270336; i += 131072) hTz[i] = z;   // hT both buffers
    for (int i = base; i < 262144; i += 131072) cxz[i] = z;   // cx
    for (int i = base; i < 2048;   i += 131072) flz[i] = z;   // 8192 flags
  }
}

// ---------- fused step: all 8 waves share ONE A-panel (L1-resident) ----------
// grid 256: bid = (ch16<<5) | b  (partner bid^32 on same XCD: bid%8 = b%8)
// block 512 = 8 waves (wl 0..7). Block: 16 hy-ch (ch16) x 4 gates (M64) x FULL 256 L.
// Wave: 4 m-frags (4 gates, same 16 ch) x 2 n-frags (32 L). GN group = ch16 pair -> 2-way spin.
__global__ __launch_bounds__(512, 1) void k_step(
    const u16* __restrict__ Wpk, const u16* __restrict__ xT, u16* __restrict__ hT,
    const float* __restrict__ cb, const float* __restrict__ gnw, const float* __restrict__ gnb,
    float* __restrict__ cx, float* __restrict__ out,
    float* __restrict__ stats, int* __restrict__ flags, int t) {
  const int bid = blockIdx.x;
  const int b = bid & 31, ch16 = bid >> 5;
  const int tid = threadIdx.x, wave = tid >> 6, lane = tid & 63;
  const int wl = wave;
  const int l15 = lane & 15, q = lane >> 4;
  const int cgrp = q << 4;

  __shared__ __align__(16) char ldsx[33792];   // 264 rows x 128 B (x, swizzled)
  __shared__ __align__(16) char ldsh[67584];   // 264 rows x 256 B (h, swizzled)
  __shared__ __align__(16) char hl[8192];      // 256 l x 32 B (16 ch bf16, 16B-granule swizzled)
  __shared__ float red[8][4][2];
  __shared__ float smu[4], srs[4];

  const u16* hTr = hT + (t & 1) * 1081344;
  u16* hTw = hT + ((t + 1) & 1) * 1081344;

  // ---- issue x(t) staging (4-5/thread), then h(t) staging (8-9/thread) ----
  {
    const char* gx = (const char*)(xT + ((t << 5) + b) * 16896);
    for (int i = tid; i < 2112; i += 512) gl_lds16(gx + (i << 4), ldsx + (i << 4));
  }
  __builtin_amdgcn_sched_barrier(0);
  {
    const char* gh = (const char*)hTr + b * 67584;
    for (int i = tid; i < 4224; i += 512) gl_lds16(gh + (i << 4), ldsh + (i << 4));
  }
  __builtin_amdgcn_sched_barrier(0);
  // vmcnt(8): every thread has 8-9 h-loads outstanding -> drains all (older) x-loads
  asm volatile("s_waitcnt vmcnt(8)" ::: "memory");
  __builtin_amdgcn_s_barrier();
  __builtin_amdgcn_sched_barrier(0);

  f32x4 zero4 = {0.f, 0.f, 0.f, 0.f};
  f32x4 acc[4][2];
  #pragma unroll
  for (int g = 0; g < 4; ++g) { acc[g][0] = zero4; acc[g][1] = zero4; }

  // A-panel base: BLOCK-uniform -> all 8 waves read identical addresses (L1 broadcast)
  const s16x8* Wv = (const s16x8*)Wpk;
  const int abase = ((ch16 >> 1) << 3) + ((ch16 & 1) << 2);

  // ---- phase 1: 10 x-chunks (kk<2, ldsx only) while h staging lands ----
  #pragma unroll
  for (int tap = 0; tap < 5; ++tap) {
    #pragma unroll
    for (int kk = 0; kk < 2; ++kk) {
      const int cc = tap * 6 + kk;
      const s16x8* Wb = Wv + (((cc << 5) + abase) << 6) + lane;
      s16x8 av[4], bv[2];
      #pragma unroll
      for (int g = 0; g < 4; ++g) av[g] = Wb[g << 6];   // imm offsets 0/1K/2K/3K
      #pragma unroll
      for (int ni = 0; ni < 2; ++ni) {
        const int rr = (wl << 5) + (ni << 4) + l15 + tap;
        const int sw = (rr & 7) << 4;
        bv[ni] = *(const s16x8*)(ldsx + (rr << 7) + (((kk << 6) + cgrp) ^ sw));
      }
      #pragma unroll
      for (int g = 0; g < 4; ++g) {
        acc[g][0] = __builtin_amdgcn_mfma_f32_16x16x32_bf16(av[g], bv[0], acc[g][0], 0, 0, 0);
        acc[g][1] = __builtin_amdgcn_mfma_f32_16x16x32_bf16(av[g], bv[1], acc[g][1], 0, 0, 0);
      }
    }
  }
  __builtin_amdgcn_sched_barrier(0);
  asm volatile("s_waitcnt vmcnt(0)" ::: "memory");
  __builtin_amdgcn_s_barrier();
  __builtin_amdgcn_sched_barrier(0);

  // ---- phase 2: 20 h-chunks (kk2 0..3, ldsh) ----
  #pragma unroll
  for (int tap = 0; tap < 5; ++tap) {
    #pragma unroll
    for (int kk2 = 0; kk2 < 4; ++kk2) {
      const int cc = tap * 6 + kk2 + 2;
      const s16x8* Wb = Wv + (((cc << 5) + abase) << 6) + lane;
      s16x8 av[4], bv[2];
      #pragma unroll
      for (int g = 0; g < 4; ++g) av[g] = Wb[g << 6];
      #pragma unroll
      for (int ni = 0; ni < 2; ++ni) {
        const int rr = (wl << 5) + (ni << 4) + l15 + tap;
        const int sw = (rr & 7) << 4;
        bv[ni] = *(const s16x8*)(ldsh + (rr << 8) + (((kk2 << 6) + cgrp) ^ sw));
      }
      #pragma unroll
      for (int g = 0; g < 4; ++g) {
        acc[g][0] = __builtin_amdgcn_mfma_f32_16x16x32_bf16(av[g], bv[0], acc[g][0], 0, 0, 0);
        acc[g][1] = __builtin_amdgcn_mfma_f32_16x16x32_bf16(av[g], bv[1], acc[g][1], 0, 0, 0);
      }
    }
  }

  // ---- +bias, per-gate partial stats (16 ch x 256 L; group = ch16 pair) ----
  const int chq = (ch16 << 4) + (q << 2);   // hy-ch base for r=0
  float sum4[4], sq4[4];
  #pragma unroll
  for (int g = 0; g < 4; ++g) {
    const f32x4 bias = *(const f32x4*)(cb + (g << 7) + chq);
    sum4[g] = 0.f; sq4[g] = 0.f;
    #pragma unroll
    for (int ni = 0; ni < 2; ++ni)
      #pragma unroll
      for (int r = 0; r < 4; ++r) {
        float v = acc[g][ni][r] + bias[r];
        acc[g][ni][r] = v;
        sum4[g] += v; sq4[g] += v * v;
      }
  }
  // preload pointwise params + cx (hides L2 latency under reduce+spin)
  f32x4 w4[4], b4[4];
  float cxv[2][4];
  #pragma unroll
  for (int g = 0; g < 4; ++g) {
    w4[g] = *(const f32x4*)(gnw + (g << 7) + chq);
    b4[g] = *(const f32x4*)(gnb + (g << 7) + chq);
  }
  #pragma unroll
  for (int ni = 0; ni < 2; ++ni) {
    const int l = (wl << 5) + (ni << 4) + l15;
    #pragma unroll
    for (int r = 0; r < 4; ++r)
      cxv[ni][r] = cx[(b << 15) + ((chq + r) << 8) + l];
  }
  #pragma unroll
  for (int off = 1; off < 64; off <<= 1) {
    #pragma unroll
    for (int g = 0; g < 4; ++g) {
      sum4[g] += __shfl_xor(sum4[g], off);
      sq4[g]  += __shfl_xor(sq4[g], off);
    }
  }
  if (lane == 0) {
    #pragma unroll
    for (int g = 0; g < 4; ++g) { red[wave][g][0] = sum4[g]; red[wave][g][1] = sq4[g]; }
  }
  __syncthreads();

  // ---- partner spin (ch16^1): tid0 sums red, 32B exchange, fixed-order sum ----
  const int sidx = (((t << 5) + b) << 3) + ch16;
  if (tid == 0) {
    float* sp = stats + (sidx << 3);
    #pragma unroll
    for (int g = 0; g < 4; ++g) {
      float s = 0.f, qv = 0.f;
      #pragma unroll
      for (int w = 0; w < 8; ++w) { s += red[w][g][0]; qv += red[w][g][1]; }
      __hip_atomic_store(sp + (g << 1),     s,  __ATOMIC_RELAXED, __HIP_MEMORY_SCOPE_AGENT);
      __hip_atomic_store(sp + (g << 1) + 1, qv, __ATOMIC_RELAXED, __HIP_MEMORY_SCOPE_AGENT);
    }
    __hip_atomic_store(&flags[sidx], 1, __ATOMIC_RELEASE, __HIP_MEMORY_SCOPE_AGENT);
    while (__hip_atomic_load(&flags[sidx ^ 1], __ATOMIC_RELAXED, __HIP_MEMORY_SCOPE_AGENT) == 0)
      __builtin_amdgcn_s_sleep(2);
    __builtin_amdgcn_fence(__ATOMIC_ACQUIRE, "agent");
    const float* pe = stats + ((sidx & ~1) << 3);   // even ch16 first -> identical in both partners
    const float* po = stats + ((sidx | 1) << 3);
    const float inv = 1.0f / 8192.0f;               // group = 32 ch x 256 L
    #pragma unroll
    for (int g = 0; g < 4; ++g) {
      float s = __hip_atomic_load(pe + (g << 1), __ATOMIC_RELAXED, __HIP_MEMORY_SCOPE_AGENT)
              + __hip_atomic_load(po + (g << 1), __ATOMIC_RELAXED, __HIP_MEMORY_SCOPE_AGENT);
      float qv = __hip_atomic_load(pe + (g << 1) + 1, __ATOMIC_RELAXED, __HIP_MEMORY_SCOPE_AGENT)
               + __hip_atomic_load(po + (g << 1) + 1, __ATOMIC_RELAXED, __HIP_MEMORY_SCOPE_AGENT);
      float m = s * inv;
      smu[g] = m;
      srs[g] = rsqrtf(qv * inv - m * m + EPS);
    }
  }
  __syncthreads();

  // ---- GN apply + LSTM pointwise (thread-local, all 4 gates in registers) ----
  const float mu0 = smu[0], mu1 = smu[1], mu2 = smu[2], mu3 = smu[3];
  const float rs0 = srs[0], rs1 = srs[1], rs2 = srs[2], rs3 = srs[3];
  float* outp = out + (((t << 5) + b) << 15);
  #pragma unroll
  for (int ni = 0; ni < 2; ++ni) {
    const int l = (wl << 5) + (ni << 4) + l15;
    u16 hp[4];
    #pragma unroll
    for (int r = 0; r < 4; ++r) {
      const int c = chq + r;
      float vi = (acc[0][ni][r] - mu0) * rs0 * w4[0][r] + b4[0][r];
      float vf = (acc[1][ni][r] - mu1) * rs1 * w4[1][r] + b4[1][r];
      float vg = (acc[2][ni][r] - mu2) * rs2 * w4[2][r] + b4[2][r];
      float vo = (acc[3][ni][r] - mu3) * rs3 * w4[3][r] + b4[3][r];
      float cyv = sigm(vf) * cxv[ni][r] + sigm(vi) * tanh_f(vg);
      float hyv = sigm(vo) * tanh_f(cyv);
      const int ci = (c << 8) + l;
      cx[(b << 15) + ci] = cyv;
      outp[ci] = hyv;
      hp[r] = f2bf(hyv);
      if (t == 31) {
        out[33554432 + (b << 15) + ci] = hyv;   // final hy
        out[34603008 + (b << 15) + ci] = cyv;   // final cy
      }
    }
    // 8B slot store; 16B granule position XOR-swizzled by (l&1)
    *(u64*)(hl + (l << 5) + ((q << 3) ^ ((l & 1) << 4))) = *(const u64*)hp;
  }
  __syncthreads();

  // ---- cooperative transposed h write: 16-ch stripe, full 256 L -> hTw ----
  {
    const int l = tid >> 1, k = tid & 1;
    const int row = l + 2;
    i32x4 v = *(const i32x4*)(hl + (l << 5) + ((k << 4) ^ ((l & 1) << 4)));
    const int gk = (ch16 << 1) + k;
    char* dst = (char*)hTw + b * 67584 + (row << 8) + ((gk << 4) ^ ((row & 7) << 4));
    *(i32x4*)dst = v;
  }
}

// ---------- launch ----------
extern "C" void kernel_launch(void* const* d_in, const int* in_sizes, int n_in,
                              void* d_out, int out_size, void* d_ws, size_t ws_size,
                              hipStream_t stream) {
  const float* x  = (const float*)d_in[0];
  const float* cw = (const float*)d_in[1];
  const float* cb = (const float*)d_in[2];
  const float* gw = (const float*)d_in[3];
  const float* gb = (const float*)d_in[4];
  float* out = (float*)d_out;
  char* ws = (char*)d_ws;

  u16*   Wpk   = (u16*)(ws);                 //     983,040 B
  u16*   xT    = (u16*)(ws + 983040);        //  34,603,008 B
  u16*   hT    = (u16*)(ws + 35586048);      //   4,325,376 B (ping-pong)
  float* cx    = (float*)(ws + 39911424);    //   4,194,304 B
  float* stats = (float*)(ws + 44105728);    //     262,144 B
  int*   flags = (int*)(ws + 44367872);      //      32,768 B  (~44.4 MB)

  k_setup<<<3456, 256, 0, stream>>>(cw, Wpk, x, xT, (i32x4*)hT, (i32x4*)cx, (i32x4*)flags);
  for (int t = 0; t < 32; ++t)
    k_step<<<256, 512, 0, stream>>>(Wpk, xT, hT, cb, gw, gb, cx, out, stats, flags, t);
}